// Round 6
// baseline (248.445 us; speedup 1.0000x reference)
//
#include <hip/hip_runtime.h>

// LocallyConnected3DFlipout:
//   out[b,p,f] = sum_k patch[b,p,k]*loc[p,k,f]
//              + sign_out[b,p,f]*sum_k (x*sign_in)patch[b,p,k]*(softplus(rho)*eps)[p,k,f]
//              + bias[f]
// patch k = c*27 + (kd*9+kh*3+kw).
//
// R13: 2-wide ow register blocking to cut x/sign load count per output 1.5x.
// Evidence chain:
//  - R12 ablation: weight path fully DMA-pipelined off the critical path
//    (bank conflicts 0, no stage VALU, FETCH 76MB) -> dur UNCHANGED (~93us).
//    The only remaining latency: 54 x/sign_in global loads per thread-tile,
//    L3-served (per-XCD x+sign working set ~5MB > 4MB L2), feeding FMAs.
//    VALUBusy*dur = const ~20-31us across ALL rounds -> dur = VALU/VALUBusy
//    with VALUBusy capped by exposed x-load latency.
//  - Occupancy tiers step at VGPR 64/128/256: R7@124 and R9@92 are the SAME
//    4-waves/SIMD tier (why R9 was null). Occupancy is fixed; cut loads.
// Design: thread owns outputs (p0, p0+1), same row (pairs start even, row=28
// wide -> never wraps). Per tap-row: 4 x-float4 + 4 s-float4 loads (columns
// ow..ow+3) serve both outputs -> 36 loads/output vs 54. Y=x*s shared.
// 16 accumulators; VGPR must stay <=128 (same tier as R7's 124).
// Single kernel again (R12's A+B split cost ~15-20us extra for nothing).
// Stage: R10-style hoisted loads, grouped 2 rounds at a time (6 float4 live)
// to bound pressure at 256 threads. R8/R11 lessons: no launch_bounds clamp,
// no bulk register prefetch.

constexpr int Bn   = 32;
constexpr int Dn   = 30;
constexpr int Cn   = 4;
constexpr int ODn  = 28;
constexpr int Pn   = ODn * ODn * ODn;   // 21952
constexpr int Tt   = 27;
constexpr int Kn   = Tt * Cn;           // 108
constexpr int PPB  = 16;                // positions per tile (8 ow-pairs)
constexpr int NT   = Pn / PPB;          // 1372 tiles
constexpr int THREADS = 256;            // 8 pairs x 32 batches
constexpr int WSTRIDE = Kn + 1;         // 109 uint4/p
constexpr int GRID = NT;

__device__ __forceinline__ unsigned bf16rne(float f) {
    unsigned u = __float_as_uint(f);
    return (u + 0x7fffu + ((u >> 16) & 1u)) >> 16;
}
__device__ __forceinline__ float bflo(unsigned u) { return __uint_as_float(u << 16); }
__device__ __forceinline__ float bfhi(unsigned u) { return __uint_as_float(u & 0xffff0000u); }

__device__ __forceinline__ uint4 pack_w(const float4 L, const float4 R, const float4 E) {
    float nx = (R.x > 15.f ? R.x : __logf(1.f + __expf(R.x))) * E.x;
    float ny = (R.y > 15.f ? R.y : __logf(1.f + __expf(R.y))) * E.y;
    float nz = (R.z > 15.f ? R.z : __logf(1.f + __expf(R.z))) * E.z;
    float nw = (R.w > 15.f ? R.w : __logf(1.f + __expf(R.w))) * E.w;
    uint4 pk;
    pk.x = bf16rne(L.x) | (bf16rne(L.y) << 16);
    pk.y = bf16rne(L.z) | (bf16rne(L.w) << 16);
    pk.z = bf16rne(nx)  | (bf16rne(ny) << 16);
    pk.w = bf16rne(nz)  | (bf16rne(nw) << 16);
    return pk;
}

__global__ __launch_bounds__(THREADS) void lc3d_flipout_kernel(
    const float* __restrict__ x,        // [B,30,30,30,4]
    const float* __restrict__ loc,      // [P,108,4]
    const float* __restrict__ rho,      // [P,108,4]
    const float* __restrict__ bias,     // [4]
    const float* __restrict__ eps,      // [P,108,4]
    const float* __restrict__ sgn_in,   // [B,30,30,30,4]
    const float* __restrict__ sgn_out,  // [B,P,4]
    float* __restrict__ out)            // [B,P,4]
{
    __shared__ uint4 wsh[PPB * WSTRIDE];   // 27,904 B

    const int tid = threadIdx.x;

    // ---- XCD-contiguous tile remap (block i -> XCD i%8) ----
    const int xcd  = blockIdx.x & 7;
    const int slot = blockIdx.x >> 3;
    const int Tx = (xcd < 4) ? xcd * 172 : 688 + (xcd - 4) * 171;
    const int p_base = (Tx + slot) * PPB;

    // ---- Stage weights: 1728 uint4 = 6*256 + 192 tail; 2 rounds hoisted
    // per group (6 float4 live) to bound register pressure. ----
    {
        const float4* loc4 = (const float4*)loc + (size_t)p_base * Kn;
        const float4* rho4 = (const float4*)rho + (size_t)p_base * Kn;
        const float4* eps4 = (const float4*)eps + (size_t)p_base * Kn;
#define STG2(ga, gb)                                                         \
        {                                                                    \
            const int g0 = tid + (ga), g1 = tid + (gb);                      \
            const float4 La = loc4[g0], Ra = rho4[g0], Ea = eps4[g0];        \
            const float4 Lb = loc4[g1], Rb = rho4[g1], Eb = eps4[g1];        \
            { const int p_ = g0 / Kn, k_ = g0 - p_ * Kn;                     \
              wsh[p_ * WSTRIDE + k_] = pack_w(La, Ra, Ea); }                 \
            { const int p_ = g1 / Kn, k_ = g1 - p_ * Kn;                     \
              wsh[p_ * WSTRIDE + k_] = pack_w(Lb, Rb, Eb); }                 \
        }
        STG2(0, 256)
        STG2(512, 768)
        STG2(1024, 1280)
        if (tid < PPB * Kn - 1536) {
            const int g = tid + 1536;
            const int p_ = g / Kn, k_ = g - p_ * Kn;
            wsh[p_ * WSTRIDE + k_] = pack_w(loc4[g], rho4[g], eps4[g]);
        }
#undef STG2
    }
    __syncthreads();

    // ---- Compute: lane = (b, j); thread owns outputs p0 = base+2j, p0+1 ----
    const int j = tid & 7;
    const int b = tid >> 3;             // 0..31
    const int p0 = p_base + 2 * j;      // even; pair (p0, p0+1) never wraps row
    const int od = p0 / (ODn * ODn);
    const int prem = p0 - od * (ODn * ODn);
    const int oh = prem / ODn;
    const int ow = prem - oh * ODn;     // even, <= 26 -> columns ow..ow+3 <= 29
    const float4* x4 = (const float4*)x;
    const float4* s4 = (const float4*)sgn_in;
    const size_t v0 = (((size_t)b * Dn + od) * Dn + oh) * Dn + ow;
    const uint4* wp0 = wsh + (2 * j) * WSTRIDE;
    const uint4* wp1 = wp0 + WSTRIDE;

    float a00=0.f,a01=0.f,a02=0.f,a03=0.f, n00=0.f,n01=0.f,n02=0.f,n03=0.f;
    float a10=0.f,a11=0.f,a12=0.f,a13=0.f, n10=0.f,n11=0.f,n12=0.f,n13=0.f;

    // out0 at column ow uses cols ow+kw; out1 uses cols ow+1+kw.
#define CH1(c, t, xa, ya, xb, yb)                                            \
    {                                                                        \
        const uint4 w0 = wp0[(c) * Tt + (t)];                                \
        const uint4 w1 = wp1[(c) * Tt + (t)];                                \
        a00 = fmaf(xa, bflo(w0.x), a00); a01 = fmaf(xa, bfhi(w0.x), a01);    \
        a02 = fmaf(xa, bflo(w0.y), a02); a03 = fmaf(xa, bfhi(w0.y), a03);    \
        n00 = fmaf(ya, bflo(w0.z), n00); n01 = fmaf(ya, bfhi(w0.z), n01);    \
        n02 = fmaf(ya, bflo(w0.w), n02); n03 = fmaf(ya, bfhi(w0.w), n03);    \
        a10 = fmaf(xb, bflo(w1.x), a10); a11 = fmaf(xb, bfhi(w1.x), a11);    \
        a12 = fmaf(xb, bflo(w1.y), a12); a13 = fmaf(xb, bfhi(w1.y), a13);    \
        n10 = fmaf(yb, bflo(w1.z), n10); n11 = fmaf(yb, bfhi(w1.z), n11);    \
        n12 = fmaf(yb, bflo(w1.w), n12); n13 = fmaf(yb, bfhi(w1.w), n13);    \
    }

#define KWC(kd, kh, kw, XA, YA, XB, YB)                                      \
    {                                                                        \
        const int t = ((kd) * 3 + (kh)) * 3 + (kw);                          \
        CH1(0, t, XA.x, YA.x, XB.x, YB.x)                                    \
        CH1(1, t, XA.y, YA.y, XB.y, YB.y)                                    \
        CH1(2, t, XA.z, YA.z, XB.z, YB.z)                                    \
        CH1(3, t, XA.w, YA.w, XB.w, YB.w)                                    \
    }

#define TAPROW(kd, kh)                                                       \
    {                                                                        \
        const int roff = ((kd) * Dn + (kh)) * Dn;                            \
        const float4 X0 = x4[v0 + roff + 0];                                 \
        const float4 X1 = x4[v0 + roff + 1];                                 \
        const float4 X2 = x4[v0 + roff + 2];                                 \
        const float4 X3 = x4[v0 + roff + 3];                                 \
        const float4 S0 = s4[v0 + roff + 0];                                 \
        const float4 S1 = s4[v0 + roff + 1];                                 \
        const float4 S2 = s4[v0 + roff + 2];                                 \
        const float4 S3 = s4[v0 + roff + 3];                                 \
        float4 Y0, Y1, Y2, Y3;                                               \
        Y0.x = X0.x * S0.x; Y0.y = X0.y * S0.y;                              \
        Y0.z = X0.z * S0.z; Y0.w = X0.w * S0.w;                              \
        Y1.x = X1.x * S1.x; Y1.y = X1.y * S1.y;                              \
        Y1.z = X1.z * S1.z; Y1.w = X1.w * S1.w;                              \
        Y2.x = X2.x * S2.x; Y2.y = X2.y * S2.y;                              \
        Y2.z = X2.z * S2.z; Y2.w = X2.w * S2.w;                              \
        Y3.x = X3.x * S3.x; Y3.y = X3.y * S3.y;                              \
        Y3.z = X3.z * S3.z; Y3.w = X3.w * S3.w;                              \
        KWC(kd, kh, 0, X0, Y0, X1, Y1)                                       \
        KWC(kd, kh, 1, X1, Y1, X2, Y2)                                       \
        KWC(kd, kh, 2, X2, Y2, X3, Y3)                                       \
    }

    #pragma unroll
    for (int kd = 0; kd < 3; ++kd) {
        TAPROW(kd, 0)
        TAPROW(kd, 1)
        TAPROW(kd, 2)
    }
#undef TAPROW
#undef KWC
#undef CH1

    // ---- Epilogue: two adjacent outputs; 8 j-threads per b write 256B ----
    const float4 bi = *(const float4*)bias;
    const size_t ob0 = (size_t)b * Pn + p0;
    const float4 so0 = ((const float4*)sgn_out)[ob0];
    const float4 so1 = ((const float4*)sgn_out)[ob0 + 1];
    float4 o0, o1;
    o0.x = fmaf(so0.x, n00, a00) + bi.x;
    o0.y = fmaf(so0.y, n01, a01) + bi.y;
    o0.z = fmaf(so0.z, n02, a02) + bi.z;
    o0.w = fmaf(so0.w, n03, a03) + bi.w;
    o1.x = fmaf(so1.x, n10, a10) + bi.x;
    o1.y = fmaf(so1.y, n11, a11) + bi.y;
    o1.z = fmaf(so1.z, n12, a12) + bi.z;
    o1.w = fmaf(so1.w, n13, a13) + bi.w;
    ((float4*)out)[ob0]     = o0;
    ((float4*)out)[ob0 + 1] = o1;
}

extern "C" void kernel_launch(void* const* d_in, const int* in_sizes, int n_in,
                              void* d_out, int out_size, void* d_ws, size_t ws_size,
                              hipStream_t stream) {
    const float* x    = (const float*)d_in[0];
    const float* loc  = (const float*)d_in[1];
    const float* rho  = (const float*)d_in[2];
    const float* bias = (const float*)d_in[3];
    const float* eps  = (const float*)d_in[4];
    const float* si   = (const float*)d_in[5];
    const float* so   = (const float*)d_in[6];
    float* out = (float*)d_out;

    lc3d_flipout_kernel<<<dim3(GRID), dim3(THREADS), 0, stream>>>(
        x, loc, rho, bias, eps, si, so, out);
}

// Round 7
// 236.119 us; speedup vs baseline: 1.0522x; 1.0522x over previous
//
#include <hip/hip_runtime.h>

// LocallyConnected3DFlipout:
//   out[b,p,f] = sum_k patch[b,p,k]*loc[p,k,f]
//              + sign_out[b,p,f]*sum_k (x*sign_in)patch[b,p,k]*(softplus(rho)*eps)[p,k,f]
//              + bias[f]
// patch k = c*27 + (kd*9+kh*3+kw).
//
// R14: K-split across waves — halve the per-wave load chain at CONSTANT VGPR.
// Evidence chain:
//  - R12 ablation: weight path fully off critical path -> dur unchanged.
//    Bottleneck = per-thread serial chain of 54 x/sign loads feeding FMAs.
//  - dur ~= VALU_time/VALUBusy in every round; VALUBusy capped 21-37%.
//  - R10: halving per-thread work at fixed VGPR raised VALUBusy 26->36
//    (only lever that ever moved it). R13: same idea via ow-blocking grew
//    VGPR to 132 -> occupancy cliff (tier at 128) -> 131us. Lesson: never
//    grow per-thread state.
// Design: two waves split one output's K-reduction (taps 0-13 / 14-26).
//  - tid = khalf(1b) | b(5b) | pl(3b): khalf is wave-uniform (bits>=6) ->
//    no divergence; each wave runs a fully unrolled 14- or 13-tap body with
//    compile-time LDS immediate offsets.
//  - Per-thread: 28 loads (was 54), same 8 accumulators -> VGPR ~ R10's 84.
//  - 2744 tiles (PPB=8) x 8 waves = 21952 waves, 2x R10, each half the chain.
//  - Recombine: khalf=1 writes partial sums to LDS scratch (reuses weight
//    slab, 8KB), khalf=0 adds + epilogue. 2 barriers, ~2% cost.
//  - XCD-contiguous: 2744 = 8*343 exact. Stage: R10-style hoisted loads.
// R8/R11 lessons intact: no launch_bounds min-waves, no register prefetch.

constexpr int Bn   = 32;
constexpr int Dn   = 30;
constexpr int Cn   = 4;
constexpr int ODn  = 28;
constexpr int Pn   = ODn * ODn * ODn;   // 21952
constexpr int Tt   = 27;
constexpr int Kn   = Tt * Cn;           // 108
constexpr int PPB  = 8;                 // positions per tile
constexpr int NT   = Pn / PPB;          // 2744 tiles = 8 * 343
constexpr int TPX  = NT / 8;            // 343
constexpr int THREADS = 512;            // 8 pos x 32 b x 2 khalf
constexpr int WSTRIDE = Kn + 1;         // 109 uint4/p
constexpr int GRID = NT;
constexpr int STAGE_UNITS = PPB * Kn;   // 864

__device__ __forceinline__ unsigned bf16rne(float f) {
    unsigned u = __float_as_uint(f);
    return (u + 0x7fffu + ((u >> 16) & 1u)) >> 16;
}
__device__ __forceinline__ float bflo(unsigned u) { return __uint_as_float(u << 16); }
__device__ __forceinline__ float bfhi(unsigned u) { return __uint_as_float(u & 0xffff0000u); }

__device__ __forceinline__ uint4 pack_w(const float4 L, const float4 R, const float4 E) {
    float nx = (R.x > 15.f ? R.x : __logf(1.f + __expf(R.x))) * E.x;
    float ny = (R.y > 15.f ? R.y : __logf(1.f + __expf(R.y))) * E.y;
    float nz = (R.z > 15.f ? R.z : __logf(1.f + __expf(R.z))) * E.z;
    float nw = (R.w > 15.f ? R.w : __logf(1.f + __expf(R.w))) * E.w;
    uint4 pk;
    pk.x = bf16rne(L.x) | (bf16rne(L.y) << 16);
    pk.y = bf16rne(L.z) | (bf16rne(L.w) << 16);
    pk.z = bf16rne(nx)  | (bf16rne(ny) << 16);
    pk.w = bf16rne(nz)  | (bf16rne(nw) << 16);
    return pk;
}

__global__ __launch_bounds__(THREADS) void lc3d_flipout_kernel(
    const float* __restrict__ x,        // [B,30,30,30,4]
    const float* __restrict__ loc,      // [P,108,4]
    const float* __restrict__ rho,      // [P,108,4]
    const float* __restrict__ bias,     // [4]
    const float* __restrict__ eps,      // [P,108,4]
    const float* __restrict__ sgn_in,   // [B,30,30,30,4]
    const float* __restrict__ sgn_out,  // [B,P,4]
    float* __restrict__ out)            // [B,P,4]
{
    __shared__ uint4 wsh[PPB * WSTRIDE];   // 13,952 B (scratch overlay later)

    const int tid = threadIdx.x;

    // ---- XCD-contiguous tile remap (block i -> XCD i%8); 343/XCD exact ----
    const int xcd  = blockIdx.x & 7;
    const int slot = blockIdx.x >> 3;
    const int p_base = (xcd * TPX + slot) * PPB;

    // ---- Stage weights: 864 uint4 over 512 threads, loads hoisted ----
    {
        const float4* loc4 = (const float4*)loc + (size_t)p_base * Kn;
        const float4* rho4 = (const float4*)rho + (size_t)p_base * Kn;
        const float4* eps4 = (const float4*)eps + (size_t)p_base * Kn;
        const bool two = tid < (STAGE_UNITS - THREADS);       // tid < 352
        const int g0 = tid;
        const int g1 = two ? tid + THREADS : tid;             // dup-safe
        const float4 L0 = loc4[g0], R0 = rho4[g0], E0 = eps4[g0];
        const float4 L1 = loc4[g1], R1 = rho4[g1], E1 = eps4[g1];
        { const int p_ = g0 / Kn, k_ = g0 - p_ * Kn;
          wsh[p_ * WSTRIDE + k_] = pack_w(L0, R0, E0); }
        if (two) {
            const int p_ = g1 / Kn, k_ = g1 - p_ * Kn;
            wsh[p_ * WSTRIDE + k_] = pack_w(L1, R1, E1);
        }
    }
    __syncthreads();

    // ---- Compute: tid = khalf(1) | b(5) | pl(3); khalf wave-uniform ----
    const int pl = tid & 7;
    const int b  = (tid >> 3) & 31;
    const int kh = tid >> 8;            // 0: taps 0-13, 1: taps 14-26
    const int p  = p_base + pl;
    const int od = p / (ODn * ODn);
    const int prem = p - od * (ODn * ODn);
    const int oh = prem / ODn;
    const int ow = prem - oh * ODn;
    const float4* x4 = (const float4*)x;
    const float4* s4 = (const float4*)sgn_in;
    const size_t v0 = (((size_t)b * Dn + od) * Dn + oh) * Dn + ow;
    const uint4* wp = wsh + pl * WSTRIDE;

    float a0=0.f,a1=0.f,a2=0.f,a3=0.f, n0=0.f,n1=0.f,n2=0.f,n3=0.f;

#define CHAN(c, t, x_c, s_c)                                                 \
    {                                                                        \
        const uint4 wv = wp[(c) * Tt + (t)];                                 \
        a0 = fmaf(x_c, bflo(wv.x), a0); a1 = fmaf(x_c, bfhi(wv.x), a1);      \
        a2 = fmaf(x_c, bflo(wv.y), a2); a3 = fmaf(x_c, bfhi(wv.y), a3);      \
        const float ya = (x_c) * (s_c);                                      \
        n0 = fmaf(ya, bflo(wv.z), n0); n1 = fmaf(ya, bfhi(wv.z), n1);        \
        n2 = fmaf(ya, bflo(wv.w), n2); n3 = fmaf(ya, bfhi(wv.w), n3);        \
    }

#define TAP(t)                                                               \
    {                                                                        \
        constexpr int kd_ = (t) / 9, kh_ = ((t) % 9) / 3, kw_ = (t) % 3;     \
        const float4 xa = x4[v0 + (kd_ * Dn + kh_) * Dn + kw_];              \
        const float4 sa = s4[v0 + (kd_ * Dn + kh_) * Dn + kw_];              \
        CHAN(0, t, xa.x, sa.x)                                               \
        CHAN(1, t, xa.y, sa.y)                                               \
        CHAN(2, t, xa.z, sa.z)                                               \
        CHAN(3, t, xa.w, sa.w)                                               \
    }

    if (kh == 0) {      // wave-uniform branch: taps 0..13
        TAP(0)  TAP(1)  TAP(2)  TAP(3)  TAP(4)  TAP(5)  TAP(6)
        TAP(7)  TAP(8)  TAP(9)  TAP(10) TAP(11) TAP(12) TAP(13)
    } else {            // taps 14..26
        TAP(14) TAP(15) TAP(16) TAP(17) TAP(18) TAP(19) TAP(20)
        TAP(21) TAP(22) TAP(23) TAP(24) TAP(25) TAP(26)
    }
#undef TAP
#undef CHAN

    // ---- K-recombine through LDS (reuse weight slab as scratch) ----
    __syncthreads();                    // all weight reads done
    float4* sc = (float4*)wsh;          // [2][256] float4 = 8 KB
    if (kh == 1) {
        sc[tid - 256]       = make_float4(a0, a1, a2, a3);
        sc[256 + tid - 256] = make_float4(n0, n1, n2, n3);
    }
    __syncthreads();
    if (kh == 0) {
        const float4 pa = sc[tid];
        const float4 pn = sc[256 + tid];
        a0 += pa.x; a1 += pa.y; a2 += pa.z; a3 += pa.w;
        n0 += pn.x; n1 += pn.y; n2 += pn.z; n3 += pn.w;

        // ---- Epilogue: coalesced (8 consecutive p per b-group) ----
        const float4 bi = *(const float4*)bias;
        const size_t ob = (size_t)b * Pn + p;
        const float4 so = ((const float4*)sgn_out)[ob];
        float4 o;
        o.x = fmaf(so.x, n0, a0) + bi.x;
        o.y = fmaf(so.y, n1, a1) + bi.y;
        o.z = fmaf(so.z, n2, a2) + bi.z;
        o.w = fmaf(so.w, n3, a3) + bi.w;
        ((float4*)out)[ob] = o;
    }
}

extern "C" void kernel_launch(void* const* d_in, const int* in_sizes, int n_in,
                              void* d_out, int out_size, void* d_ws, size_t ws_size,
                              hipStream_t stream) {
    const float* x    = (const float*)d_in[0];
    const float* loc  = (const float*)d_in[1];
    const float* rho  = (const float*)d_in[2];
    const float* bias = (const float*)d_in[3];
    const float* eps  = (const float*)d_in[4];
    const float* si   = (const float*)d_in[5];
    const float* so   = (const float*)d_in[6];
    float* out = (float*)d_out;

    lc3d_flipout_kernel<<<dim3(GRID), dim3(THREADS), 0, stream>>>(
        x, loc, rho, bias, eps, si, so, out);
}

// Round 8
// 209.727 us; speedup vs baseline: 1.1846x; 1.1258x over previous
//
#include <hip/hip_runtime.h>

// LocallyConnected3DFlipout:
//   out[b,p,f] = sum_k patch[b,p,k]*loc[p,k,f]
//              + sign_out[b,p,f]*sum_k (x*sign_in)patch[b,p,k]*(softplus(rho)*eps)[p,k,f]
//              + bias[f]
// patch k = c*27 + (kd*9+kh*3+kw).
//
// R15: eliminate the sign_in load stream. Evidence chain:
//  - R12 ablation: weights fully off critical path -> dur unchanged. The
//    bottleneck is the per-thread chain of x/sign global loads (L3, ~600cy).
//  - R10: halving the chain at constant VGPR raised VALUBusy 26->36 (works).
//  - R13/R14: chain-halving that grows VGPR (132/128) -> occupancy cliff,
//    131-135us. Lesson: shorten the chain with ZERO state growth.
// Design: sign_in is Rademacher (+-1), so x*sign_in == sign-bit XOR.
//  - pack_signs kernel: S8[b][d][h][w] byte = 4 channel sign bits. 922 KB
//    (rows padded to 32B) -> permanently L2/L3-hot (115 KB per XCD).
//  - Main kernel = R10 chassis verbatim (geometry, stage, epilogue), but the
//    27 sign_in float4 loads become 18 L2-hot dword loads (2/tap-row,
//    64-bit funnel once per row), signs applied as XOR 0x80000000 masks.
//  - Chain: 54 far loads -> 27 far + 18 near. Sign traffic (13.8MB) gone.
//  - Bit-exact vs R10 (+-1 mul == XOR, incl. +-0): absmax must not change.
// R8/R11/R13/R14 lessons: no launch_bounds clamp, no reg prefetch, no
// per-thread state growth. Fallback to R10 kernel if ws too small.

constexpr int Bn   = 32;
constexpr int Dn   = 30;
constexpr int Cn   = 4;
constexpr int ODn  = 28;
constexpr int Pn   = ODn * ODn * ODn;   // 21952
constexpr int Tt   = 27;
constexpr int Kn   = Tt * Cn;           // 108
constexpr int PPB  = 16;                // positions per tile
constexpr int NT   = Pn / PPB;          // 1372 tiles
constexpr int THREADS = 512;            // 16 pos x 32 batches, 1 batch/thread
constexpr int WSTRIDE = Kn + 1;         // 109 uint4/p
constexpr int GRID = NT;

constexpr int NCELL = Bn * Dn * Dn * Dn;          // 864000
constexpr size_t WS_NEEDED = (size_t)Bn * Dn * Dn * 32;  // rows padded to 32B = 921600

__device__ __forceinline__ unsigned bf16rne(float f) {
    unsigned u = __float_as_uint(f);
    return (u + 0x7fffu + ((u >> 16) & 1u)) >> 16;
}
__device__ __forceinline__ float bflo(unsigned u) { return __uint_as_float(u << 16); }
__device__ __forceinline__ float bfhi(unsigned u) { return __uint_as_float(u & 0xffff0000u); }

__device__ __forceinline__ uint4 pack_w(const float4 L, const float4 R, const float4 E) {
    float nx = (R.x > 15.f ? R.x : __logf(1.f + __expf(R.x))) * E.x;
    float ny = (R.y > 15.f ? R.y : __logf(1.f + __expf(R.y))) * E.y;
    float nz = (R.z > 15.f ? R.z : __logf(1.f + __expf(R.z))) * E.z;
    float nw = (R.w > 15.f ? R.w : __logf(1.f + __expf(R.w))) * E.w;
    uint4 pk;
    pk.x = bf16rne(L.x) | (bf16rne(L.y) << 16);
    pk.y = bf16rne(L.z) | (bf16rne(L.w) << 16);
    pk.z = bf16rne(nx)  | (bf16rne(ny) << 16);
    pk.w = bf16rne(nz)  | (bf16rne(nw) << 16);
    return pk;
}

// ============ Kernel A: pack sign bits, 1 byte per cell ============
__global__ __launch_bounds__(256) void pack_signs(
    const float* __restrict__ sgn_in, unsigned char* __restrict__ s8)
{
    const int idx = blockIdx.x * 256 + threadIdx.x;
    if (idx >= NCELL) return;
    const float4 s = ((const float4*)sgn_in)[idx];   // coalesced 16B
    const unsigned u =
        (__float_as_uint(s.x) >> 31)
      | ((__float_as_uint(s.y) >> 31) << 1)
      | ((__float_as_uint(s.z) >> 31) << 2)
      | ((__float_as_uint(s.w) >> 31) << 3);
    const int w = idx % 30;
    const int row = idx / 30;
    s8[(size_t)row * 32 + w] = (unsigned char)u;
}

// ============ Main kernel: R10 chassis + sign-byte XOR path ============
__global__ __launch_bounds__(THREADS) void lc3d_flipout_kernel(
    const float* __restrict__ x,        // [B,30,30,30,4]
    const float* __restrict__ loc,      // [P,108,4]
    const float* __restrict__ rho,      // [P,108,4]
    const float* __restrict__ bias,     // [4]
    const float* __restrict__ eps,      // [P,108,4]
    const unsigned char* __restrict__ s8, // packed signs [B*30*30][32]
    const float* __restrict__ sgn_out,  // [B,P,4]
    float* __restrict__ out)            // [B,P,4]
{
    __shared__ uint4 wsh[PPB * WSTRIDE];   // 27,904 B

    const int tid = threadIdx.x;

    // ---- XCD-contiguous tile remap (block i -> XCD i%8) ----
    const int xcd  = blockIdx.x & 7;
    const int slot = blockIdx.x >> 3;
    const int Tx = (xcd < 4) ? xcd * 172 : 688 + (xcd - 4) * 171;
    const int p_base = (Tx + slot) * PPB;

    // ---- Stage weights: 1728 uint4 = 3*512 + 192 tail, loads hoisted ----
    {
        const float4* loc4 = (const float4*)loc + (size_t)p_base * Kn;
        const float4* rho4 = (const float4*)rho + (size_t)p_base * Kn;
        const float4* eps4 = (const float4*)eps + (size_t)p_base * Kn;
        const int g0 = tid, g1 = tid + 512, g2 = tid + 1024;
        const float4 L0 = loc4[g0], R0 = rho4[g0], E0 = eps4[g0];
        const float4 L1 = loc4[g1], R1 = rho4[g1], E1 = eps4[g1];
        const float4 L2 = loc4[g2], R2 = rho4[g2], E2 = eps4[g2];
        { const int p_ = g0 / Kn, k_ = g0 - p_ * Kn; wsh[p_ * WSTRIDE + k_] = pack_w(L0, R0, E0); }
        { const int p_ = g1 / Kn, k_ = g1 - p_ * Kn; wsh[p_ * WSTRIDE + k_] = pack_w(L1, R1, E1); }
        { const int p_ = g2 / Kn, k_ = g2 - p_ * Kn; wsh[p_ * WSTRIDE + k_] = pack_w(L2, R2, E2); }
        if (tid < PPB * Kn - 1536) {
            const int g3 = tid + 1536;
            const int p_ = g3 / Kn, k_ = g3 - p_ * Kn;
            wsh[p_ * WSTRIDE + k_] = pack_w(loc4[g3], rho4[g3], eps4[g3]);
        }
    }
    __syncthreads();

    // ---- Compute: lane = (b, pl), 1 batch/thread, 8 accumulators ----
    const int pl = tid & 15;
    const int b  = tid >> 4;            // 0..31
    const int p  = p_base + pl;
    const int od = p / (ODn * ODn);
    const int prem = p - od * (ODn * ODn);
    const int oh = prem / ODn;
    const int ow = prem - oh * ODn;     // 0..27
    const float4* x4 = (const float4*)x;
    const size_t v0 = (((size_t)b * Dn + od) * Dn + oh) * Dn + ow;
    const uint4* wp = wsh + pl * WSTRIDE;

    // Sign-byte row base: rows padded to 32B; aligned dword pair covers
    // cells ow..ow+2 (A = ow&~3 <= 24, A+7 <= 31, in-row).
    const unsigned char* srb = s8 + ((size_t)(b * Dn + od) * Dn + oh) * 32 + (ow & ~3);
    const int sh = 8 * (ow & 3);

    float a0=0.f,a1=0.f,a2=0.f,a3=0.f, n0=0.f,n1=0.f,n2=0.f,n3=0.f;

    // byte bt has channel-c sign at bit c; (bt<<(31-c))&0x80000000 is the
    // XOR mask. c=0 needs no AND (upper bits shift out).
#define CHAN(c, t, x_c, bt)                                                  \
    {                                                                        \
        const uint4 wv = wp[(c) * Tt + (t)];                                 \
        a0 = fmaf(x_c, bflo(wv.x), a0); a1 = fmaf(x_c, bfhi(wv.x), a1);      \
        a2 = fmaf(x_c, bflo(wv.y), a2); a3 = fmaf(x_c, bfhi(wv.y), a3);      \
        const unsigned m_ = ((bt) << (31 - (c))) & 0x80000000u;              \
        const float ya = __uint_as_float(__float_as_uint(x_c) ^ m_);         \
        n0 = fmaf(ya, bflo(wv.z), n0); n1 = fmaf(ya, bfhi(wv.z), n1);        \
        n2 = fmaf(ya, bflo(wv.w), n2); n3 = fmaf(ya, bfhi(wv.w), n3);        \
    }

#define TAPROW(kd, khh)                                                      \
    {                                                                        \
        const int roff = ((kd) * Dn + (khh)) * Dn;                           \
        const float4 X0 = x4[v0 + roff + 0];                                 \
        const float4 X1 = x4[v0 + roff + 1];                                 \
        const float4 X2 = x4[v0 + roff + 2];                                 \
        const unsigned char* sr = srb + ((kd) * Dn + (khh)) * 32;            \
        const unsigned sw0 = *(const unsigned*)(sr);                         \
        const unsigned sw1 = *(const unsigned*)(sr + 4);                     \
        const unsigned long long sv =                                        \
            (((unsigned long long)sw1 << 32) | sw0) >> sh;                   \
        const unsigned bt0 = (unsigned)sv;                                   \
        const unsigned bt1 = (unsigned)(sv >> 8);                            \
        const unsigned bt2 = (unsigned)(sv >> 16);                           \
        const int tb = ((kd) * 3 + (khh)) * 3;                               \
        CHAN(0, tb + 0, X0.x, bt0) CHAN(1, tb + 0, X0.y, bt0)                \
        CHAN(2, tb + 0, X0.z, bt0) CHAN(3, tb + 0, X0.w, bt0)                \
        CHAN(0, tb + 1, X1.x, bt1) CHAN(1, tb + 1, X1.y, bt1)                \
        CHAN(2, tb + 1, X1.z, bt1) CHAN(3, tb + 1, X1.w, bt1)                \
        CHAN(0, tb + 2, X2.x, bt2) CHAN(1, tb + 2, X2.y, bt2)                \
        CHAN(2, tb + 2, X2.z, bt2) CHAN(3, tb + 2, X2.w, bt2)                \
    }

    #pragma unroll
    for (int kd = 0; kd < 3; ++kd) {
        TAPROW(kd, 0)
        TAPROW(kd, 1)
        TAPROW(kd, 2)
    }
#undef TAPROW
#undef CHAN

    // ---- Epilogue: coalesced (16 consecutive p per b-group) ----
    const float4 bi = *(const float4*)bias;
    const size_t ob = (size_t)b * Pn + p;
    const float4 so = ((const float4*)sgn_out)[ob];
    float4 o;
    o.x = fmaf(so.x, n0, a0) + bi.x;
    o.y = fmaf(so.y, n1, a1) + bi.y;
    o.z = fmaf(so.z, n2, a2) + bi.z;
    o.w = fmaf(so.w, n3, a3) + bi.w;
    ((float4*)out)[ob] = o;
}

// ============ Fallback: verified R10 kernel (87us) ============
__global__ __launch_bounds__(THREADS) void lc3d_fallback(
    const float* __restrict__ x, const float* __restrict__ loc,
    const float* __restrict__ rho, const float* __restrict__ bias,
    const float* __restrict__ eps, const float* __restrict__ sgn_in,
    const float* __restrict__ sgn_out, float* __restrict__ out)
{
    __shared__ uint4 wsh[PPB * WSTRIDE];
    const int tid = threadIdx.x;
    const int xcd  = blockIdx.x & 7;
    const int slot = blockIdx.x >> 3;
    const int Tx = (xcd < 4) ? xcd * 172 : 688 + (xcd - 4) * 171;
    const int p_base = (Tx + slot) * PPB;
    {
        const float4* loc4 = (const float4*)loc + (size_t)p_base * Kn;
        const float4* rho4 = (const float4*)rho + (size_t)p_base * Kn;
        const float4* eps4 = (const float4*)eps + (size_t)p_base * Kn;
        const int g0 = tid, g1 = tid + 512, g2 = tid + 1024;
        const float4 L0 = loc4[g0], R0 = rho4[g0], E0 = eps4[g0];
        const float4 L1 = loc4[g1], R1 = rho4[g1], E1 = eps4[g1];
        const float4 L2 = loc4[g2], R2 = rho4[g2], E2 = eps4[g2];
        { const int p_ = g0 / Kn, k_ = g0 - p_ * Kn; wsh[p_ * WSTRIDE + k_] = pack_w(L0, R0, E0); }
        { const int p_ = g1 / Kn, k_ = g1 - p_ * Kn; wsh[p_ * WSTRIDE + k_] = pack_w(L1, R1, E1); }
        { const int p_ = g2 / Kn, k_ = g2 - p_ * Kn; wsh[p_ * WSTRIDE + k_] = pack_w(L2, R2, E2); }
        if (tid < PPB * Kn - 1536) {
            const int g3 = tid + 1536;
            const int p_ = g3 / Kn, k_ = g3 - p_ * Kn;
            wsh[p_ * WSTRIDE + k_] = pack_w(loc4[g3], rho4[g3], eps4[g3]);
        }
    }
    __syncthreads();
    const int pl = tid & 15;
    const int b  = tid >> 4;
    const int p  = p_base + pl;
    const int od = p / (ODn * ODn);
    const int prem = p - od * (ODn * ODn);
    const int oh = prem / ODn;
    const int ow = prem - oh * ODn;
    const float4* x4 = (const float4*)x;
    const float4* s4 = (const float4*)sgn_in;
    const size_t v0 = (((size_t)b * Dn + od) * Dn + oh) * Dn + ow;
    const uint4* wp = wsh + pl * WSTRIDE;
    float a0=0.f,a1=0.f,a2=0.f,a3=0.f, n0=0.f,n1=0.f,n2=0.f,n3=0.f;
#define CHANF(c, t, x_c, s_c)                                                \
    {                                                                        \
        const uint4 wv = wp[(c) * Tt + (t)];                                 \
        a0 = fmaf(x_c, bflo(wv.x), a0); a1 = fmaf(x_c, bfhi(wv.x), a1);      \
        a2 = fmaf(x_c, bflo(wv.y), a2); a3 = fmaf(x_c, bfhi(wv.y), a3);      \
        const float ya = (x_c) * (s_c);                                      \
        n0 = fmaf(ya, bflo(wv.z), n0); n1 = fmaf(ya, bfhi(wv.z), n1);        \
        n2 = fmaf(ya, bflo(wv.w), n2); n3 = fmaf(ya, bfhi(wv.w), n3);        \
    }
    #pragma unroll
    for (int kd = 0; kd < 3; ++kd)
        #pragma unroll
        for (int kh = 0; kh < 3; ++kh) {
            const int roff = (kd * Dn + kh) * Dn;
            #pragma unroll
            for (int kw = 0; kw < 3; ++kw) {
                const int t = (kd * 3 + kh) * 3 + kw;
                const float4 xa = x4[v0 + roff + kw];
                const float4 sa = s4[v0 + roff + kw];
                CHANF(0, t, xa.x, sa.x) CHANF(1, t, xa.y, sa.y)
                CHANF(2, t, xa.z, sa.z) CHANF(3, t, xa.w, sa.w)
            }
        }
#undef CHANF
    const float4 bi = *(const float4*)bias;
    const size_t ob = (size_t)b * Pn + p;
    const float4 so = ((const float4*)sgn_out)[ob];
    float4 o;
    o.x = fmaf(so.x, n0, a0) + bi.x;
    o.y = fmaf(so.y, n1, a1) + bi.y;
    o.z = fmaf(so.z, n2, a2) + bi.z;
    o.w = fmaf(so.w, n3, a3) + bi.w;
    ((float4*)out)[ob] = o;
}

extern "C" void kernel_launch(void* const* d_in, const int* in_sizes, int n_in,
                              void* d_out, int out_size, void* d_ws, size_t ws_size,
                              hipStream_t stream) {
    const float* x    = (const float*)d_in[0];
    const float* loc  = (const float*)d_in[1];
    const float* rho  = (const float*)d_in[2];
    const float* bias = (const float*)d_in[3];
    const float* eps  = (const float*)d_in[4];
    const float* si   = (const float*)d_in[5];
    const float* so   = (const float*)d_in[6];
    float* out = (float*)d_out;

    if (d_ws != nullptr && ws_size >= WS_NEEDED) {
        pack_signs<<<dim3((NCELL + 255) / 256), dim3(256), 0, stream>>>(
            si, (unsigned char*)d_ws);
        lc3d_flipout_kernel<<<dim3(GRID), dim3(THREADS), 0, stream>>>(
            x, loc, rho, bias, eps, (const unsigned char*)d_ws, so, out);
    } else {
        lc3d_fallback<<<dim3(GRID), dim3(THREADS), 0, stream>>>(
            x, loc, rho, bias, eps, si, so, out);
    }
}